// Round 3
// baseline (197.256 us; speedup 1.0000x reference)
//
#include <hip/hip_runtime.h>
#include <hip/hip_bf16.h>

// B=4, S=4096, D=1024, H=64.
// qs = LN(x@Wq), ks = LN(x@Wk), vs = x@Wv; out = softmax(qs ks^T/8) @ vs.
//  - LN rows have ||r||=8 exactly -> |score| <= 8 -> no online softmax; exp2
//    with log2(e) folded into q's LN scale (raw v_exp_f32, no mul).
//  - k_proj: NO LDS. A-frags (X, fp32->bf16 cvt) and B-frags (WT, L1/L2
//    resident) straight from global in fragment order; register ping-pong
//    prefetch; barrier-free K loop.
//  - k_attn: KV split 8 (ws permitting; else 4) for 6 blocks/CU; K/V tile
//    prefetched into registers across the barrier.

typedef __bf16 bf16x8 __attribute__((ext_vector_type(8)));
typedef __bf16 bf16x4 __attribute__((ext_vector_type(4)));
typedef float f32x4 __attribute__((ext_vector_type(4)));

#define NROW 16384
#define DD   1024
#define HH   64
#define SS   4096
#define LS   68      // LDS row stride (elems); 34 dw == 2 mod 32 -> free alias

static __device__ inline unsigned short f2bf_u(float x) {
  __bf16 b = (__bf16)x;
  return __builtin_bit_cast(unsigned short, b);
}
// 8 bf16 from an 8B-aligned LDS address: two ds_read_b64
static __device__ inline bf16x8 ld8(const __bf16* p) {
  bf16x4 lo = *reinterpret_cast<const bf16x4*>(p);
  bf16x4 hi = *reinterpret_cast<const bf16x4*>(p + 4);
  return __builtin_shufflevector(lo, hi, 0, 1, 2, 3, 4, 5, 6, 7);
}

// ---------------------------------------------------------------- kernel 1
__global__ __launch_bounds__(256) void k_transpose_w(
    const float* __restrict__ Wq, const float* __restrict__ Wk,
    const float* __restrict__ Wv, __bf16* __restrict__ WT) {
  int idx = blockIdx.x * 256 + threadIdx.x;   // 0..196607
  int mat = idx >> 16;
  int rem = idx & 65535;                      // k*64 + h (coalesced read)
  int k = rem >> 6, h = rem & 63;
  const float* W = (mat == 0) ? Wq : ((mat == 1) ? Wk : Wv);
  WT[(size_t)(mat * 64 + h) * DD + k] = (__bf16)W[rem];
}

// ---------------------------------------------------------------- kernel 2
// LDS-free projection GEMM. Block = 128 thr (2 waves), 32 rows; grid 512.
// Wave w: rows Mb+16w+m. Per K-step: A = X row frag (fp32->bf16), B = 12 WT
// row frags (L1-hit). Ping-pong register prefetch; no barriers.
__global__ __launch_bounds__(128, 2) void k_proj(
    const float* __restrict__ X, const __bf16* __restrict__ WT,
    __bf16* __restrict__ qb, __bf16* __restrict__ kbp, __bf16* __restrict__ vT) {
  const int t = threadIdx.x, lane = t & 63, w = t >> 6;
  const int quad = lane >> 4, m = lane & 15;
  const int Mb = blockIdx.x * 32;
  const int row = Mb + 16 * w + m;
  const float* xp = &X[(size_t)row * DD + quad * 8];
  const __bf16* wp = &WT[(size_t)m * DD + quad * 8];

  f32x4 acc[12];
#pragma unroll
  for (int i = 0; i < 12; i++) acc[i] = (f32x4){0.f, 0.f, 0.f, 0.f};

  float4 xa = *reinterpret_cast<const float4*>(xp);
  float4 xb = *reinterpret_cast<const float4*>(xp + 4);
  bf16x8 wn[12];
#pragma unroll
  for (int nt = 0; nt < 12; nt++)
    wn[nt] = *reinterpret_cast<const bf16x8*>(wp + (size_t)nt * 16 * DD);

  for (int ko = 0; ko < DD; ko += 32) {
    bf16x8 a;
    a[0] = (__bf16)xa.x; a[1] = (__bf16)xa.y;
    a[2] = (__bf16)xa.z; a[3] = (__bf16)xa.w;
    a[4] = (__bf16)xb.x; a[5] = (__bf16)xb.y;
    a[6] = (__bf16)xb.z; a[7] = (__bf16)xb.w;
    bf16x8 wc[12];
#pragma unroll
    for (int nt = 0; nt < 12; nt++) wc[nt] = wn[nt];
    if (ko + 32 < DD) {   // prefetch next K-step while MFMAs run
      xa = *reinterpret_cast<const float4*>(xp + ko + 32);
      xb = *reinterpret_cast<const float4*>(xp + ko + 36);
#pragma unroll
      for (int nt = 0; nt < 12; nt++)
        wn[nt] = *reinterpret_cast<const bf16x8*>(
            wp + (size_t)nt * 16 * DD + ko + 32);
    }
#pragma unroll
    for (int nt = 0; nt < 12; nt++)
      acc[nt] = __builtin_amdgcn_mfma_f32_16x16x32_bf16(a, wc[nt], acc[nt], 0, 0, 0);
  }

  // fused LayerNorm over H=64 for q (mat 0, with 1/8*log2e folded) and k
#pragma unroll
  for (int mat = 0; mat < 2; mat++) {
#pragma unroll
    for (int reg = 0; reg < 4; reg++) {
      float s = 0.f, s2 = 0.f;
#pragma unroll
      for (int ntl = 0; ntl < 4; ntl++) {
        float x = acc[mat * 4 + ntl][reg];
        s += x; s2 += x * x;
      }
#pragma unroll
      for (int off = 1; off < 16; off <<= 1) {
        s += __shfl_xor(s, off, 64);
        s2 += __shfl_xor(s2, off, 64);
      }
      float mu = s * (1.0f / 64.0f);
      float var = s2 * (1.0f / 64.0f) - mu * mu;
      float rstd = rsqrtf(var + 1e-5f);
      float scl = (mat == 0) ? 0.125f * 1.44269504f * rstd : rstd;
#pragma unroll
      for (int ntl = 0; ntl < 4; ntl++)
        acc[mat * 4 + ntl][reg] = (acc[mat * 4 + ntl][reg] - mu) * scl;
    }
  }

  const int rowbase = Mb + 16 * w + quad * 4;
#pragma unroll
  for (int nt = 0; nt < 4; nt++)
#pragma unroll
    for (int reg = 0; reg < 4; reg++) {
      qb[(size_t)(rowbase + reg) * HH + m + 16 * nt] = (__bf16)acc[nt][reg];
      kbp[(size_t)(rowbase + reg) * HH + m + 16 * nt] = (__bf16)acc[4 + nt][reg];
    }
  const int b = Mb >> 12;
  const int s0 = (Mb & 4095) + 16 * w + quad * 4;
#pragma unroll
  for (int nt = 0; nt < 4; nt++) {
    ushort4 pk = make_ushort4(f2bf_u(acc[8 + nt][0]), f2bf_u(acc[8 + nt][1]),
                              f2bf_u(acc[8 + nt][2]), f2bf_u(acc[8 + nt][3]));
    *reinterpret_cast<ushort4*>(
        &vT[((size_t)(b * 64) + m + 16 * nt) * SS + s0]) = pk;
  }
}

// ---------------------------------------------------------------- kernel 3
// Attention partial: block = (64 q-rows) x (KV split of SS>>spbits keys).
// No online softmax (|log2-score| <= 11.6). O transposed (A=V^T, B=P); l via
// ones-MFMA. Next K/V tile prefetched into regs before the write barrier.
__global__ __launch_bounds__(256, 6) void k_attn(
    const __bf16* __restrict__ qb, const __bf16* __restrict__ kbp,
    const __bf16* __restrict__ vT, float* __restrict__ Op,
    float* __restrict__ lp, int spbits) {
  __shared__ __bf16 Klds[64 * LS];      // [key][h]
  __shared__ __bf16 Vlds[64 * LS];      // [h][key]
  __shared__ __bf16 Plds[4][16 * LS];   // per-wave [q][key]
  const int t = threadIdx.x, lane = t & 63, w = t >> 6;
  const int quad = lane >> 4, m = lane & 15;
  const int nsp = 1 << spbits;
  const int qt = blockIdx.x >> spbits, sp = blockIdx.x & (nsp - 1);
  const int KPS = SS >> spbits;
  const int Mb = qt * 64;
  const int b = Mb >> 12;
  const size_t kvbase = (size_t)b * SS * HH;

  bf16x8 qf[2];
  {
    const int row = Mb + 16 * w + m;
    qf[0] = *reinterpret_cast<const bf16x8*>(&qb[(size_t)row * HH + quad * 8]);
    qf[1] = *reinterpret_cast<const bf16x8*>(&qb[(size_t)row * HH + 32 + quad * 8]);
  }
  bf16x8 ones;
#pragma unroll
  for (int i = 0; i < 8; i++) ones[i] = (__bf16)1.0f;

  f32x4 O[4], lac;
#pragma unroll
  for (int i = 0; i < 4; i++) O[i] = (f32x4){0.f, 0.f, 0.f, 0.f};
  lac = (f32x4){0.f, 0.f, 0.f, 0.f};

  // staging indices (2 chunks/thread)
  const int c0row = t >> 3, ck0 = (t & 7) * 8;       // chunk 0: rows 0..31
  const int c1row = c0row + 32;                      // chunk 1: rows 32..63
  const int kb_lo = sp * KPS, kb_hi = kb_lo + KPS;

  uint4 kd0, kd1, vd0, vd1;
  {
    kd0 = *reinterpret_cast<const uint4*>(&kbp[kvbase + (size_t)(kb_lo + c0row) * HH + ck0]);
    kd1 = *reinterpret_cast<const uint4*>(&kbp[kvbase + (size_t)(kb_lo + c1row) * HH + ck0]);
    vd0 = *reinterpret_cast<const uint4*>(&vT[(size_t)(b * 64 + c0row) * SS + kb_lo + ck0]);
    vd1 = *reinterpret_cast<const uint4*>(&vT[(size_t)(b * 64 + c1row) * SS + kb_lo + ck0]);
  }

  for (int kb0 = kb_lo; kb0 < kb_hi; kb0 += 64) {
    {
      __bf16* kp0 = &Klds[c0row * LS + ck0];
      __bf16* kp1 = &Klds[c1row * LS + ck0];
      __bf16* vp0 = &Vlds[c0row * LS + ck0];
      __bf16* vp1 = &Vlds[c1row * LS + ck0];
      *reinterpret_cast<uint2*>(kp0) = make_uint2(kd0.x, kd0.y);
      *reinterpret_cast<uint2*>(kp0 + 4) = make_uint2(kd0.z, kd0.w);
      *reinterpret_cast<uint2*>(kp1) = make_uint2(kd1.x, kd1.y);
      *reinterpret_cast<uint2*>(kp1 + 4) = make_uint2(kd1.z, kd1.w);
      *reinterpret_cast<uint2*>(vp0) = make_uint2(vd0.x, vd0.y);
      *reinterpret_cast<uint2*>(vp0 + 4) = make_uint2(vd0.z, vd0.w);
      *reinterpret_cast<uint2*>(vp1) = make_uint2(vd1.x, vd1.y);
      *reinterpret_cast<uint2*>(vp1 + 4) = make_uint2(vd1.z, vd1.w);
    }
    __syncthreads();
    if (kb0 + 64 < kb_hi) {   // prefetch next tile; in flight during compute
      kd0 = *reinterpret_cast<const uint4*>(&kbp[kvbase + (size_t)(kb0 + 64 + c0row) * HH + ck0]);
      kd1 = *reinterpret_cast<const uint4*>(&kbp[kvbase + (size_t)(kb0 + 64 + c1row) * HH + ck0]);
      vd0 = *reinterpret_cast<const uint4*>(&vT[(size_t)(b * 64 + c0row) * SS + kb0 + 64 + ck0]);
      vd1 = *reinterpret_cast<const uint4*>(&vT[(size_t)(b * 64 + c1row) * SS + kb0 + 64 + ck0]);
    }

    f32x4 sc[4];
#pragma unroll
    for (int nt = 0; nt < 4; nt++) sc[nt] = (f32x4){0.f, 0.f, 0.f, 0.f};
#pragma unroll
    for (int kk = 0; kk < 2; kk++)
#pragma unroll
      for (int nt = 0; nt < 4; nt++) {
        bf16x8 bf = ld8(&Klds[(m + 16 * nt) * LS + 32 * kk + quad * 8]);
        sc[nt] = __builtin_amdgcn_mfma_f32_16x16x32_bf16(qf[kk], bf, sc[nt], 0, 0, 0);
      }

    __bf16* Pw = Plds[w];
#pragma unroll
    for (int nt = 0; nt < 4; nt++)
#pragma unroll
      for (int reg = 0; reg < 4; reg++)
        Pw[(quad * 4 + reg) * LS + m + 16 * nt] = (__bf16)exp2f(sc[nt][reg]);

#pragma unroll
    for (int kk = 0; kk < 2; kk++) {
      bf16x8 pf = ld8(&Pw[m * LS + 32 * kk + quad * 8]);
      lac = __builtin_amdgcn_mfma_f32_16x16x32_bf16(ones, pf, lac, 0, 0, 0);
#pragma unroll
      for (int ht = 0; ht < 4; ht++) {
        bf16x8 vf = ld8(&Vlds[(m + 16 * ht) * LS + 32 * kk + quad * 8]);
        O[ht] = __builtin_amdgcn_mfma_f32_16x16x32_bf16(vf, pf, O[ht], 0, 0, 0);
      }
    }
    __syncthreads();
  }

  // lane owns q-row; store permuted (quad*16 + ht*4 + reg) -> 64B/lane chunks
  const int rowg = Mb + 16 * w + m;
  float4* obase = reinterpret_cast<float4*>(
      &Op[((size_t)sp * NROW + rowg) * HH + quad * 16]);
#pragma unroll
  for (int ht = 0; ht < 4; ht++)
    obase[ht] = make_float4(O[ht][0], O[ht][1], O[ht][2], O[ht][3]);
  if (quad == 0) lp[sp * NROW + rowg] = lac[0];
}

// ---------------------------------------------------------------- kernel 4
__global__ __launch_bounds__(256) void k_comb(const float* __restrict__ Op,
                                              const float* __restrict__ lp,
                                              float* __restrict__ out, int nsp) {
  int idx = blockIdx.x * 256 + threadIdx.x;   // < NROW*HH
  int row = idx >> 6, h = idx & 63;
  int soff = ((h >> 2) & 3) * 16 + (h >> 4) * 4 + (h & 3);
  size_t sbase = (size_t)row * HH + soff;
  float o = 0.f, l = 0.f;
  for (int j = 0; j < nsp; j++) {
    o += Op[(size_t)j * NROW * HH + sbase];
    l += lp[j * NROW + row];
  }
  out[idx] = o / l;
}

// ---------------------------------------------------------------- launch
extern "C" void kernel_launch(void* const* d_in, const int* in_sizes, int n_in,
                              void* d_out, int out_size, void* d_ws, size_t ws_size,
                              hipStream_t stream) {
  const float* X  = (const float*)d_in[0];
  const float* Wq = (const float*)d_in[1];
  const float* Wk = (const float*)d_in[2];
  const float* Wv = (const float*)d_in[3];
  float* out = (float*)d_out;
  char* ws = (char*)d_ws;

  __bf16* WT  = (__bf16*)(ws);                          // 384 KB
  __bf16* qb  = (__bf16*)(ws + (size_t)512 * 1024);     // 2 MB
  __bf16* kbp = (__bf16*)(ws + (size_t)2560 * 1024);    // 2 MB
  __bf16* vT  = (__bf16*)(ws + (size_t)4608 * 1024);    // 2 MB
  float*  Op  = (float*)(ws + (size_t)6656 * 1024);     // nsp * 4 MB
  // split 8 if workspace allows (Op 32 MB + lp 512 KB), else 4
  const size_t need8 = (size_t)(6656 + 8 * 4096 + 512) * 1024;
  const int spbits = (ws_size >= need8) ? 3 : 2;
  const int nsp = 1 << spbits;
  float* lp = (float*)(ws + (size_t)(6656 + nsp * 4096) * 1024);

  hipLaunchKernelGGL(k_transpose_w, dim3(768), dim3(256), 0, stream, Wq, Wk, Wv, WT);
  hipLaunchKernelGGL(k_proj, dim3(NROW / 32), dim3(128), 0, stream, X, WT, qb, kbp, vT);
  hipLaunchKernelGGL(k_attn, dim3((NROW / 64) * nsp), dim3(256), 0, stream,
                     qb, kbp, vT, Op, lp, spbits);
  hipLaunchKernelGGL(k_comb, dim3(NROW * HH / 256), dim3(256), 0, stream,
                     Op, lp, out, nsp);
}

// Round 4
// 195.441 us; speedup vs baseline: 1.0093x; 1.0093x over previous
//
#include <hip/hip_runtime.h>
#include <hip/hip_bf16.h>

// B=4, S=4096, D=1024, H=64.
// qs = LN(x@Wq), ks = LN(x@Wk), vs = x@Wv; out = softmax(qs ks^T/8) @ vs.
//  - LN rows have ||r||=8 exactly -> |score| <= 8 -> no online softmax; exp2
//    with log2(e) folded into q's LN scale.
//  - k_proj: wave-split-K, barrier-free K-loop, 16 rows/block, grid 1024
//    (4 blocks/CU). X streamed once coalesced; WT from L2. Cross-wave acc
//    reduce via LDS once at end; wave 0 does LN + stores.
//  - k_attn: KV split 8 (ws permitting; else 4); K/V tile prefetched into
//    registers across the barrier. LDS stride 68 (2-way alias = free).

typedef __bf16 bf16x8 __attribute__((ext_vector_type(8)));
typedef __bf16 bf16x4 __attribute__((ext_vector_type(4)));
typedef float f32x4 __attribute__((ext_vector_type(4)));

#define NROW 16384
#define DD   1024
#define HH   64
#define SS   4096
#define LS   68

static __device__ inline unsigned short f2bf_u(float x) {
  __bf16 b = (__bf16)x;
  return __builtin_bit_cast(unsigned short, b);
}
static __device__ inline bf16x8 ld8(const __bf16* p) {
  bf16x4 lo = *reinterpret_cast<const bf16x4*>(p);
  bf16x4 hi = *reinterpret_cast<const bf16x4*>(p + 4);
  return __builtin_shufflevector(lo, hi, 0, 1, 2, 3, 4, 5, 6, 7);
}

// ---------------------------------------------------------------- kernel 1
__global__ __launch_bounds__(256) void k_transpose_w(
    const float* __restrict__ Wq, const float* __restrict__ Wk,
    const float* __restrict__ Wv, __bf16* __restrict__ WT) {
  int idx = blockIdx.x * 256 + threadIdx.x;   // 0..196607
  int mat = idx >> 16;
  int rem = idx & 65535;                      // k*64 + h (coalesced read)
  int k = rem >> 6, h = rem & 63;
  const float* W = (mat == 0) ? Wq : ((mat == 1) ? Wk : Wv);
  WT[(size_t)(mat * 64 + h) * DD + k] = (__bf16)W[rem];
}

// ---------------------------------------------------------------- kernel 2
// Wave-split-K projection. Block = 16 rows, 4 waves; wave w: k in
// [256w, 256w+256). 12 N-tiles (q 0-3, k 4-7, v 8-11), 8 K-iters, no
// barriers in loop. bn[nt] reloaded in place right after its MFMA use.
__global__ __launch_bounds__(256, 4) void k_proj(
    const float* __restrict__ X, const __bf16* __restrict__ WT,
    __bf16* __restrict__ qb, __bf16* __restrict__ kbp, __bf16* __restrict__ vT) {
  __shared__ float red[2][64][52];   // 2 reduce slots, padded lane stride
  const int t = threadIdx.x, lane = t & 63, w = t >> 6;
  const int quad = lane >> 4, m = lane & 15;
  const int Mb = blockIdx.x * 16;
  const int k0 = w * 256 + quad * 8;
  const float* xp = &X[(size_t)(Mb + m) * DD + k0];
  const __bf16* wtp = &WT[(size_t)m * DD + k0];

  f32x4 acc[12];
#pragma unroll
  for (int i = 0; i < 12; i++) acc[i] = (f32x4){0.f, 0.f, 0.f, 0.f};

  float4 xa = *reinterpret_cast<const float4*>(xp);
  float4 xb = *reinterpret_cast<const float4*>(xp + 4);
  bf16x8 bn[12];
#pragma unroll
  for (int nt = 0; nt < 12; nt++)
    bn[nt] = *reinterpret_cast<const bf16x8*>(wtp + (size_t)nt * 16 * DD);

#pragma unroll
  for (int it = 0; it < 8; it++) {
    const int nxt = (it + 1) & 7;    // wraps to 0 on last iter (safe addrs)
    bf16x8 a;
    a[0] = (__bf16)xa.x; a[1] = (__bf16)xa.y;
    a[2] = (__bf16)xa.z; a[3] = (__bf16)xa.w;
    a[4] = (__bf16)xb.x; a[5] = (__bf16)xb.y;
    a[6] = (__bf16)xb.z; a[7] = (__bf16)xb.w;
    float4 nxa = *reinterpret_cast<const float4*>(xp + nxt * 32);
    float4 nxb = *reinterpret_cast<const float4*>(xp + nxt * 32 + 4);
#pragma unroll
    for (int nt = 0; nt < 12; nt++) {
      acc[nt] = __builtin_amdgcn_mfma_f32_16x16x32_bf16(a, bn[nt], acc[nt], 0, 0, 0);
      bn[nt] = *reinterpret_cast<const bf16x8*>(
          wtp + (size_t)nt * 16 * DD + nxt * 32);
    }
    xa = nxa; xb = nxb;
  }

  // cross-wave accumulator reduce: waves 2,3 -> slots; 0,1 add; 1 -> slot; 0 adds
  if (w >= 2) {
#pragma unroll
    for (int nt = 0; nt < 12; nt++)
      *reinterpret_cast<f32x4*>(&red[w - 2][lane][nt * 4]) = acc[nt];
  }
  __syncthreads();
  if (w < 2) {
#pragma unroll
    for (int nt = 0; nt < 12; nt++)
      acc[nt] += *reinterpret_cast<const f32x4*>(&red[w][lane][nt * 4]);
  }
  __syncthreads();
  if (w == 1) {
#pragma unroll
    for (int nt = 0; nt < 12; nt++)
      *reinterpret_cast<f32x4*>(&red[0][lane][nt * 4]) = acc[nt];
  }
  __syncthreads();
  if (w != 0) return;
#pragma unroll
  for (int nt = 0; nt < 12; nt++)
    acc[nt] += *reinterpret_cast<const f32x4*>(&red[0][lane][nt * 4]);

  // fused LayerNorm over H=64 for q (log2e/8 folded) and k
#pragma unroll
  for (int mat = 0; mat < 2; mat++) {
#pragma unroll
    for (int reg = 0; reg < 4; reg++) {
      float s = 0.f, s2 = 0.f;
#pragma unroll
      for (int ntl = 0; ntl < 4; ntl++) {
        float x = acc[mat * 4 + ntl][reg];
        s += x; s2 += x * x;
      }
#pragma unroll
      for (int off = 1; off < 16; off <<= 1) {
        s += __shfl_xor(s, off, 64);
        s2 += __shfl_xor(s2, off, 64);
      }
      float mu = s * (1.0f / 64.0f);
      float var = s2 * (1.0f / 64.0f) - mu * mu;
      float rstd = rsqrtf(var + 1e-5f);
      float scl = (mat == 0) ? 0.125f * 1.44269504f * rstd : rstd;
#pragma unroll
      for (int ntl = 0; ntl < 4; ntl++)
        acc[mat * 4 + ntl][reg] = (acc[mat * 4 + ntl][reg] - mu) * scl;
    }
  }

  const int rowbase = Mb + quad * 4;
#pragma unroll
  for (int nt = 0; nt < 4; nt++)
#pragma unroll
    for (int reg = 0; reg < 4; reg++) {
      qb[(size_t)(rowbase + reg) * HH + m + 16 * nt] = (__bf16)acc[nt][reg];
      kbp[(size_t)(rowbase + reg) * HH + m + 16 * nt] = (__bf16)acc[4 + nt][reg];
    }
  const int b = Mb >> 12;
  const int s0 = (Mb & 4095) + quad * 4;
#pragma unroll
  for (int nt = 0; nt < 4; nt++) {
    ushort4 pk = make_ushort4(f2bf_u(acc[8 + nt][0]), f2bf_u(acc[8 + nt][1]),
                              f2bf_u(acc[8 + nt][2]), f2bf_u(acc[8 + nt][3]));
    *reinterpret_cast<ushort4*>(
        &vT[((size_t)(b * 64) + m + 16 * nt) * SS + s0]) = pk;
  }
}

// ---------------------------------------------------------------- kernel 3
// Attention partial: block = (64 q-rows) x (KV split of SS>>spbits keys).
// No online softmax. O transposed (A=V^T, B=P); l via ones-MFMA. Next K/V
// tile prefetched into regs before the write barrier.
__global__ __launch_bounds__(256, 6) void k_attn(
    const __bf16* __restrict__ qb, const __bf16* __restrict__ kbp,
    const __bf16* __restrict__ vT, float* __restrict__ Op,
    float* __restrict__ lp, int spbits) {
  __shared__ __bf16 Klds[64 * LS];      // [key][h]
  __shared__ __bf16 Vlds[64 * LS];      // [h][key]
  __shared__ __bf16 Plds[4][16 * LS];   // per-wave [q][key]
  const int t = threadIdx.x, lane = t & 63, w = t >> 6;
  const int quad = lane >> 4, m = lane & 15;
  const int nsp = 1 << spbits;
  const int qt = blockIdx.x >> spbits, sp = blockIdx.x & (nsp - 1);
  const int KPS = SS >> spbits;
  const int Mb = qt * 64;
  const int b = Mb >> 12;
  const size_t kvbase = (size_t)b * SS * HH;

  bf16x8 qf[2];
  {
    const int row = Mb + 16 * w + m;
    qf[0] = *reinterpret_cast<const bf16x8*>(&qb[(size_t)row * HH + quad * 8]);
    qf[1] = *reinterpret_cast<const bf16x8*>(&qb[(size_t)row * HH + 32 + quad * 8]);
  }
  bf16x8 ones;
#pragma unroll
  for (int i = 0; i < 8; i++) ones[i] = (__bf16)1.0f;

  f32x4 O[4], lac;
#pragma unroll
  for (int i = 0; i < 4; i++) O[i] = (f32x4){0.f, 0.f, 0.f, 0.f};
  lac = (f32x4){0.f, 0.f, 0.f, 0.f};

  const int c0row = t >> 3, ck0 = (t & 7) * 8;
  const int c1row = c0row + 32;
  const int kb_lo = sp * KPS, kb_hi = kb_lo + KPS;

  uint4 kd0, kd1, vd0, vd1;
  {
    kd0 = *reinterpret_cast<const uint4*>(&kbp[kvbase + (size_t)(kb_lo + c0row) * HH + ck0]);
    kd1 = *reinterpret_cast<const uint4*>(&kbp[kvbase + (size_t)(kb_lo + c1row) * HH + ck0]);
    vd0 = *reinterpret_cast<const uint4*>(&vT[(size_t)(b * 64 + c0row) * SS + kb_lo + ck0]);
    vd1 = *reinterpret_cast<const uint4*>(&vT[(size_t)(b * 64 + c1row) * SS + kb_lo + ck0]);
  }

  for (int kb0 = kb_lo; kb0 < kb_hi; kb0 += 64) {
    {
      __bf16* kp0 = &Klds[c0row * LS + ck0];
      __bf16* kp1 = &Klds[c1row * LS + ck0];
      __bf16* vp0 = &Vlds[c0row * LS + ck0];
      __bf16* vp1 = &Vlds[c1row * LS + ck0];
      *reinterpret_cast<uint2*>(kp0) = make_uint2(kd0.x, kd0.y);
      *reinterpret_cast<uint2*>(kp0 + 4) = make_uint2(kd0.z, kd0.w);
      *reinterpret_cast<uint2*>(kp1) = make_uint2(kd1.x, kd1.y);
      *reinterpret_cast<uint2*>(kp1 + 4) = make_uint2(kd1.z, kd1.w);
      *reinterpret_cast<uint2*>(vp0) = make_uint2(vd0.x, vd0.y);
      *reinterpret_cast<uint2*>(vp0 + 4) = make_uint2(vd0.z, vd0.w);
      *reinterpret_cast<uint2*>(vp1) = make_uint2(vd1.x, vd1.y);
      *reinterpret_cast<uint2*>(vp1 + 4) = make_uint2(vd1.z, vd1.w);
    }
    __syncthreads();
    if (kb0 + 64 < kb_hi) {
      kd0 = *reinterpret_cast<const uint4*>(&kbp[kvbase + (size_t)(kb0 + 64 + c0row) * HH + ck0]);
      kd1 = *reinterpret_cast<const uint4*>(&kbp[kvbase + (size_t)(kb0 + 64 + c1row) * HH + ck0]);
      vd0 = *reinterpret_cast<const uint4*>(&vT[(size_t)(b * 64 + c0row) * SS + kb0 + 64 + ck0]);
      vd1 = *reinterpret_cast<const uint4*>(&vT[(size_t)(b * 64 + c1row) * SS + kb0 + 64 + ck0]);
    }

    f32x4 sc[4];
#pragma unroll
    for (int nt = 0; nt < 4; nt++) sc[nt] = (f32x4){0.f, 0.f, 0.f, 0.f};
#pragma unroll
    for (int kk = 0; kk < 2; kk++)
#pragma unroll
      for (int nt = 0; nt < 4; nt++) {
        bf16x8 bf = ld8(&Klds[(m + 16 * nt) * LS + 32 * kk + quad * 8]);
        sc[nt] = __builtin_amdgcn_mfma_f32_16x16x32_bf16(qf[kk], bf, sc[nt], 0, 0, 0);
      }

    __bf16* Pw = Plds[w];
#pragma unroll
    for (int nt = 0; nt < 4; nt++)
#pragma unroll
      for (int reg = 0; reg < 4; reg++)
        Pw[(quad * 4 + reg) * LS + m + 16 * nt] = (__bf16)exp2f(sc[nt][reg]);

#pragma unroll
    for (int kk = 0; kk < 2; kk++) {
      bf16x8 pf = ld8(&Pw[m * LS + 32 * kk + quad * 8]);
      lac = __builtin_amdgcn_mfma_f32_16x16x32_bf16(ones, pf, lac, 0, 0, 0);
#pragma unroll
      for (int ht = 0; ht < 4; ht++) {
        bf16x8 vf = ld8(&Vlds[(m + 16 * ht) * LS + 32 * kk + quad * 8]);
        O[ht] = __builtin_amdgcn_mfma_f32_16x16x32_bf16(vf, pf, O[ht], 0, 0, 0);
      }
    }
    __syncthreads();
  }

  const int rowg = Mb + 16 * w + m;
  float4* obase = reinterpret_cast<float4*>(
      &Op[((size_t)sp * NROW + rowg) * HH + quad * 16]);
#pragma unroll
  for (int ht = 0; ht < 4; ht++)
    obase[ht] = make_float4(O[ht][0], O[ht][1], O[ht][2], O[ht][3]);
  if (quad == 0) lp[sp * NROW + rowg] = lac[0];
}

// ---------------------------------------------------------------- kernel 4
__global__ __launch_bounds__(256) void k_comb(const float* __restrict__ Op,
                                              const float* __restrict__ lp,
                                              float* __restrict__ out, int nsp) {
  int idx = blockIdx.x * 256 + threadIdx.x;   // < NROW*HH
  int row = idx >> 6, h = idx & 63;
  int soff = ((h >> 2) & 3) * 16 + (h >> 4) * 4 + (h & 3);
  size_t sbase = (size_t)row * HH + soff;
  float o = 0.f, l = 0.f;
  for (int j = 0; j < nsp; j++) {
    o += Op[(size_t)j * NROW * HH + sbase];
    l += lp[j * NROW + row];
  }
  out[idx] = o / l;
}

// ---------------------------------------------------------------- launch
extern "C" void kernel_launch(void* const* d_in, const int* in_sizes, int n_in,
                              void* d_out, int out_size, void* d_ws, size_t ws_size,
                              hipStream_t stream) {
  const float* X  = (const float*)d_in[0];
  const float* Wq = (const float*)d_in[1];
  const float* Wk = (const float*)d_in[2];
  const float* Wv = (const float*)d_in[3];
  float* out = (float*)d_out;
  char* ws = (char*)d_ws;

  __bf16* WT  = (__bf16*)(ws);                          // 384 KB
  __bf16* qb  = (__bf16*)(ws + (size_t)512 * 1024);     // 2 MB
  __bf16* kbp = (__bf16*)(ws + (size_t)2560 * 1024);    // 2 MB
  __bf16* vT  = (__bf16*)(ws + (size_t)4608 * 1024);    // 2 MB
  float*  Op  = (float*)(ws + (size_t)6656 * 1024);     // nsp * 4 MB
  const size_t need8 = (size_t)(6656 + 8 * 4096 + 512) * 1024;
  const int spbits = (ws_size >= need8) ? 3 : 2;
  const int nsp = 1 << spbits;
  float* lp = (float*)(ws + (size_t)(6656 + nsp * 4096) * 1024);

  hipLaunchKernelGGL(k_transpose_w, dim3(768), dim3(256), 0, stream, Wq, Wk, Wv, WT);
  hipLaunchKernelGGL(k_proj, dim3(NROW / 16), dim3(256), 0, stream, X, WT, qb, kbp, vT);
  hipLaunchKernelGGL(k_attn, dim3((NROW / 64) * nsp), dim3(256), 0, stream,
                     qb, kbp, vT, Op, lp, spbits);
  hipLaunchKernelGGL(k_comb, dim3(NROW * HH / 256), dim3(256), 0, stream,
                     Op, lp, out, nsp);
}

// Round 6
// 164.138 us; speedup vs baseline: 1.2018x; 1.1907x over previous
//
#include <hip/hip_runtime.h>
#include <hip/hip_bf16.h>

// B=4, S=4096, D=1024, H=64.
// qs = LN(x@Wq), ks = LN(x@Wk), vs = x@Wv; out = softmax(qs ks^T/8) @ vs.
//  - LN rows have ||r||=8 exactly -> |score| <= 8 -> no online softmax; exp2
//    with log2(e) folded into q's LN scale.
//  - k_proj: r2-validated structure (wave owns 16 rows x all 12 N-tiles; LN
//    fully in registers) with BK=64 staging + register ping-pong prefetch.
//    r5's cross-wave LDS epilogue is REVERTED (failed at 6.3e-3).
//  - k_attn: KV split 8 (ws permitting); reg prefetch across barrier.
//    LDS stride 68 everywhere (2-way alias = free; 0 conflicts measured).

typedef __bf16 bf16x8 __attribute__((ext_vector_type(8)));
typedef __bf16 bf16x4 __attribute__((ext_vector_type(4)));
typedef float f32x4 __attribute__((ext_vector_type(4)));

#define NROW 16384
#define DD   1024
#define HH   64
#define SS   4096
#define LS   68

static __device__ inline unsigned short f2bf_u(float x) {
  __bf16 b = (__bf16)x;
  return __builtin_bit_cast(unsigned short, b);
}
static __device__ inline uint2 pk4f(float a, float b, float c, float d) {
  return make_uint2((unsigned)f2bf_u(a) | ((unsigned)f2bf_u(b) << 16),
                    (unsigned)f2bf_u(c) | ((unsigned)f2bf_u(d) << 16));
}
static __device__ inline bf16x8 ld8(const __bf16* p) {
  bf16x4 lo = *reinterpret_cast<const bf16x4*>(p);
  bf16x4 hi = *reinterpret_cast<const bf16x4*>(p + 4);
  return __builtin_shufflevector(lo, hi, 0, 1, 2, 3, 4, 5, 6, 7);
}

// ---------------------------------------------------------------- kernel 1
__global__ __launch_bounds__(256) void k_transpose_w(
    const float* __restrict__ Wq, const float* __restrict__ Wk,
    const float* __restrict__ Wv, __bf16* __restrict__ WT) {
  int idx = blockIdx.x * 256 + threadIdx.x;   // 0..196607
  int mat = idx >> 16;
  int rem = idx & 65535;                      // k*64 + h (coalesced read)
  int k = rem >> 6, h = rem & 63;
  const float* W = (mat == 0) ? Wq : ((mat == 1) ? Wk : Wv);
  WT[(size_t)(mat * 64 + h) * DD + k] = (__bf16)W[rem];
}

// ---------------------------------------------------------------- kernel 2
// Staged projection GEMM, r2 structure + BK=64. Block = 32 rows, 2 waves;
// wave w owns rows 16w..16w+15 x all 12 N-tiles (acc[12]); LN in registers.
__global__ __launch_bounds__(128, 2) void k_proj(
    const float* __restrict__ X, const __bf16* __restrict__ WT,
    __bf16* __restrict__ qb, __bf16* __restrict__ kbp, __bf16* __restrict__ vT) {
  __shared__ __bf16 Xs[32 * LS];    // 4352 B
  __shared__ __bf16 Ws[192 * LS];   // 26112 B
  const int t = threadIdx.x, lane = t & 63, w = t >> 6;   // w in 0..1
  const int quad = lane >> 4, m = lane & 15;
  const int Mb = blockIdx.x * 32;

  f32x4 acc[12];
#pragma unroll
  for (int i = 0; i < 12; i++) acc[i] = (f32x4){0.f, 0.f, 0.f, 0.f};

  // staging maps (fully coalesced):
  //  X: 512 float4 chunks; chunk c: row=c>>4, col=(c&15)*4
  //  W: 1536 bf16x8 chunks; chunk c: row=c>>3, col=(c&7)*8
  float4 xr[4];
  bf16x8 wr[12];
#pragma unroll
  for (int i = 0; i < 4; i++) {
    int c = t + i * 128, row = c >> 4, col = (c & 15) * 4;
    xr[i] = *reinterpret_cast<const float4*>(&X[(size_t)(Mb + row) * DD + col]);
  }
#pragma unroll
  for (int i = 0; i < 12; i++) {
    int c = t + i * 128, row = c >> 3, col = (c & 7) * 8;
    wr[i] = *reinterpret_cast<const bf16x8*>(&WT[(size_t)row * DD + col]);
  }

  for (int s = 0; s < 16; s++) {
    if (s) __syncthreads();               // prev compute done, LDS writable
#pragma unroll
    for (int i = 0; i < 4; i++) {
      int c = t + i * 128, row = c >> 4, col = (c & 15) * 4;
      *reinterpret_cast<uint2*>(&Xs[row * LS + col]) =
          pk4f(xr[i].x, xr[i].y, xr[i].z, xr[i].w);
    }
#pragma unroll
    for (int i = 0; i < 12; i++) {
      int c = t + i * 128, row = c >> 3, col = (c & 7) * 8;
      uint4 raw = __builtin_bit_cast(uint4, wr[i]);
      __bf16* wd = &Ws[row * LS + col];
      *reinterpret_cast<uint2*>(wd) = make_uint2(raw.x, raw.y);
      *reinterpret_cast<uint2*>(wd + 4) = make_uint2(raw.z, raw.w);
    }
    __syncthreads();                      // LDS ready
    if (s + 1 < 16) {                     // prefetch next stage into regs
      const int ko = (s + 1) * 64;
#pragma unroll
      for (int i = 0; i < 4; i++) {
        int c = t + i * 128, row = c >> 4, col = (c & 15) * 4;
        xr[i] = *reinterpret_cast<const float4*>(
            &X[(size_t)(Mb + row) * DD + ko + col]);
      }
#pragma unroll
      for (int i = 0; i < 12; i++) {
        int c = t + i * 128, row = c >> 3, col = (c & 7) * 8;
        wr[i] = *reinterpret_cast<const bf16x8*>(
            &WT[(size_t)row * DD + ko + col]);
      }
    }
#pragma unroll
    for (int kk = 0; kk < 2; kk++) {
      bf16x8 a = ld8(&Xs[(16 * w + m) * LS + 32 * kk + quad * 8]);
#pragma unroll
      for (int nt = 0; nt < 12; nt++) {
        bf16x8 bfr = ld8(&Ws[(16 * nt + m) * LS + 32 * kk + quad * 8]);
        acc[nt] = __builtin_amdgcn_mfma_f32_16x16x32_bf16(a, bfr, acc[nt], 0, 0, 0);
      }
    }
  }

  // ---- fused LayerNorm in registers (r2-validated), log2e folded into q
#pragma unroll
  for (int mat = 0; mat < 2; mat++) {
#pragma unroll
    for (int reg = 0; reg < 4; reg++) {
      float s = 0.f, s2 = 0.f;
#pragma unroll
      for (int ntl = 0; ntl < 4; ntl++) {
        float x = acc[mat * 4 + ntl][reg];
        s += x; s2 += x * x;
      }
#pragma unroll
      for (int off = 1; off < 16; off <<= 1) {
        s += __shfl_xor(s, off, 64);
        s2 += __shfl_xor(s2, off, 64);
      }
      float mu = s * (1.0f / 64.0f);
      float var = s2 * (1.0f / 64.0f) - mu * mu;
      float rstd = rsqrtf(var + 1e-5f);
      float scl = (mat == 0) ? 0.125f * 1.44269504f * rstd : rstd;
#pragma unroll
      for (int ntl = 0; ntl < 4; ntl++)
        acc[mat * 4 + ntl][reg] = (acc[mat * 4 + ntl][reg] - mu) * scl;
    }
  }

  const int rowbase = Mb + 16 * w + quad * 4;
#pragma unroll
  for (int nt = 0; nt < 4; nt++)
#pragma unroll
    for (int reg = 0; reg < 4; reg++) {
      qb[(size_t)(rowbase + reg) * HH + m + 16 * nt] = (__bf16)acc[nt][reg];
      kbp[(size_t)(rowbase + reg) * HH + m + 16 * nt] = (__bf16)acc[4 + nt][reg];
    }
  const int b = Mb >> 12;
  const int s0 = (Mb & 4095) + 16 * w + quad * 4;
#pragma unroll
  for (int nt = 0; nt < 4; nt++) {
    ushort4 pk = make_ushort4(f2bf_u(acc[8 + nt][0]), f2bf_u(acc[8 + nt][1]),
                              f2bf_u(acc[8 + nt][2]), f2bf_u(acc[8 + nt][3]));
    *reinterpret_cast<ushort4*>(
        &vT[((size_t)(b * 64) + m + 16 * nt) * SS + s0]) = pk;
  }
}

// ---------------------------------------------------------------- kernel 3
// Attention partial: block = (64 q-rows) x (KV split of SS>>spbits keys).
// No online softmax. O transposed (A=V^T, B=P); l via ones-MFMA. Next K/V
// tile prefetched into regs before the write barrier.
__global__ __launch_bounds__(256, 6) void k_attn(
    const __bf16* __restrict__ qb, const __bf16* __restrict__ kbp,
    const __bf16* __restrict__ vT, float* __restrict__ Op,
    float* __restrict__ lp, int spbits) {
  __shared__ __bf16 Klds[64 * LS];      // [key][h]
  __shared__ __bf16 Vlds[64 * LS];      // [h][key]
  __shared__ __bf16 Plds[4][16 * LS];   // per-wave [q][key]
  const int t = threadIdx.x, lane = t & 63, w = t >> 6;
  const int quad = lane >> 4, m = lane & 15;
  const int nsp = 1 << spbits;
  const int qt = blockIdx.x >> spbits, sp = blockIdx.x & (nsp - 1);
  const int KPS = SS >> spbits;
  const int Mb = qt * 64;
  const int b = Mb >> 12;
  const size_t kvbase = (size_t)b * SS * HH;

  bf16x8 qf[2];
  {
    const int row = Mb + 16 * w + m;
    qf[0] = *reinterpret_cast<const bf16x8*>(&qb[(size_t)row * HH + quad * 8]);
    qf[1] = *reinterpret_cast<const bf16x8*>(&qb[(size_t)row * HH + 32 + quad * 8]);
  }
  bf16x8 ones;
#pragma unroll
  for (int i = 0; i < 8; i++) ones[i] = (__bf16)1.0f;

  f32x4 O[4], lac;
#pragma unroll
  for (int i = 0; i < 4; i++) O[i] = (f32x4){0.f, 0.f, 0.f, 0.f};
  lac = (f32x4){0.f, 0.f, 0.f, 0.f};

  const int c0row = t >> 3, ck0 = (t & 7) * 8;
  const int c1row = c0row + 32;
  const int kb_lo = sp * KPS, kb_hi = kb_lo + KPS;

  uint4 kd0, kd1, vd0, vd1;
  {
    kd0 = *reinterpret_cast<const uint4*>(&kbp[kvbase + (size_t)(kb_lo + c0row) * HH + ck0]);
    kd1 = *reinterpret_cast<const uint4*>(&kbp[kvbase + (size_t)(kb_lo + c1row) * HH + ck0]);
    vd0 = *reinterpret_cast<const uint4*>(&vT[(size_t)(b * 64 + c0row) * SS + kb_lo + ck0]);
    vd1 = *reinterpret_cast<const uint4*>(&vT[(size_t)(b * 64 + c1row) * SS + kb_lo + ck0]);
  }

  for (int kb0 = kb_lo; kb0 < kb_hi; kb0 += 64) {
    {
      __bf16* kp0 = &Klds[c0row * LS + ck0];
      __bf16* kp1 = &Klds[c1row * LS + ck0];
      __bf16* vp0 = &Vlds[c0row * LS + ck0];
      __bf16* vp1 = &Vlds[c1row * LS + ck0];
      *reinterpret_cast<uint2*>(kp0) = make_uint2(kd0.x, kd0.y);
      *reinterpret_cast<uint2*>(kp0 + 4) = make_uint2(kd0.z, kd0.w);
      *reinterpret_cast<uint2*>(kp1) = make_uint2(kd1.x, kd1.y);
      *reinterpret_cast<uint2*>(kp1 + 4) = make_uint2(kd1.z, kd1.w);
      *reinterpret_cast<uint2*>(vp0) = make_uint2(vd0.x, vd0.y);
      *reinterpret_cast<uint2*>(vp0 + 4) = make_uint2(vd0.z, vd0.w);
      *reinterpret_cast<uint2*>(vp1) = make_uint2(vd1.x, vd1.y);
      *reinterpret_cast<uint2*>(vp1 + 4) = make_uint2(vd1.z, vd1.w);
    }
    __syncthreads();
    if (kb0 + 64 < kb_hi) {
      kd0 = *reinterpret_cast<const uint4*>(&kbp[kvbase + (size_t)(kb0 + 64 + c0row) * HH + ck0]);
      kd1 = *reinterpret_cast<const uint4*>(&kbp[kvbase + (size_t)(kb0 + 64 + c1row) * HH + ck0]);
      vd0 = *reinterpret_cast<const uint4*>(&vT[(size_t)(b * 64 + c0row) * SS + kb0 + 64 + ck0]);
      vd1 = *reinterpret_cast<const uint4*>(&vT[(size_t)(b * 64 + c1row) * SS + kb0 + 64 + ck0]);
    }

    f32x4 sc[4];
#pragma unroll
    for (int nt = 0; nt < 4; nt++) sc[nt] = (f32x4){0.f, 0.f, 0.f, 0.f};
#pragma unroll
    for (int kk = 0; kk < 2; kk++)
#pragma unroll
      for (int nt = 0; nt < 4; nt++) {
        bf16x8 bf = ld8(&Klds[(m + 16 * nt) * LS + 32 * kk + quad * 8]);
        sc[nt] = __builtin_amdgcn_mfma_f32_16x16x32_bf16(qf[kk], bf, sc[nt], 0, 0, 0);
      }

    __bf16* Pw = Plds[w];
#pragma unroll
    for (int nt = 0; nt < 4; nt++)
#pragma unroll
      for (int reg = 0; reg < 4; reg++)
        Pw[(quad * 4 + reg) * LS + m + 16 * nt] = (__bf16)exp2f(sc[nt][reg]);

#pragma unroll
    for (int kk = 0; kk < 2; kk++) {
      bf16x8 pf = ld8(&Pw[m * LS + 32 * kk + quad * 8]);
      lac = __builtin_amdgcn_mfma_f32_16x16x32_bf16(ones, pf, lac, 0, 0, 0);
#pragma unroll
      for (int ht = 0; ht < 4; ht++) {
        bf16x8 vf = ld8(&Vlds[(m + 16 * ht) * LS + 32 * kk + quad * 8]);
        O[ht] = __builtin_amdgcn_mfma_f32_16x16x32_bf16(vf, pf, O[ht], 0, 0, 0);
      }
    }
    __syncthreads();
  }

  const int rowg = Mb + 16 * w + m;
  float4* obase = reinterpret_cast<float4*>(
      &Op[((size_t)sp * NROW + rowg) * HH + quad * 16]);
#pragma unroll
  for (int ht = 0; ht < 4; ht++)
    obase[ht] = make_float4(O[ht][0], O[ht][1], O[ht][2], O[ht][3]);
  if (quad == 0) lp[sp * NROW + rowg] = lac[0];
}

// ---------------------------------------------------------------- kernel 4
__global__ __launch_bounds__(256) void k_comb(const float* __restrict__ Op,
                                              const float* __restrict__ lp,
                                              float* __restrict__ out, int nsp) {
  int idx = blockIdx.x * 256 + threadIdx.x;   // < NROW*HH
  int row = idx >> 6, h = idx & 63;
  int soff = ((h >> 2) & 3) * 16 + (h >> 4) * 4 + (h & 3);
  size_t sbase = (size_t)row * HH + soff;
  float o = 0.f, l = 0.f;
  for (int j = 0; j < nsp; j++) {
    o += Op[(size_t)j * NROW * HH + sbase];
    l += lp[j * NROW + row];
  }
  out[idx] = o / l;
}

// ---------------------------------------------------------------- launch
extern "C" void kernel_launch(void* const* d_in, const int* in_sizes, int n_in,
                              void* d_out, int out_size, void* d_ws, size_t ws_size,
                              hipStream_t stream) {
  const float* X  = (const float*)d_in[0];
  const float* Wq = (const float*)d_in[1];
  const float* Wk = (const float*)d_in[2];
  const float* Wv = (const float*)d_in[3];
  float* out = (float*)d_out;
  char* ws = (char*)d_ws;

  __bf16* WT  = (__bf16*)(ws);                          // 384 KB
  __bf16* qb  = (__bf16*)(ws + (size_t)512 * 1024);     // 2 MB
  __bf16* kbp = (__bf16*)(ws + (size_t)2560 * 1024);    // 2 MB
  __bf16* vT  = (__bf16*)(ws + (size_t)4608 * 1024);    // 2 MB
  float*  Op  = (float*)(ws + (size_t)6656 * 1024);     // nsp * 4 MB
  const size_t need8 = (size_t)(6656 + 8 * 4096 + 512) * 1024;
  const int spbits = (ws_size >= need8) ? 3 : 2;
  const int nsp = 1 << spbits;
  float* lp = (float*)(ws + (size_t)(6656 + nsp * 4096) * 1024);

  hipLaunchKernelGGL(k_transpose_w, dim3(768), dim3(256), 0, stream, Wq, Wk, Wv, WT);
  hipLaunchKernelGGL(k_proj, dim3(NROW / 32), dim3(128), 0, stream, X, WT, qb, kbp, vT);
  hipLaunchKernelGGL(k_attn, dim3((NROW / 64) * nsp), dim3(256), 0, stream,
                     qb, kbp, vT, Op, lp, spbits);
  hipLaunchKernelGGL(k_comb, dim3(NROW * HH / 256), dim3(256), 0, stream,
                     Op, lp, out, nsp);
}

// Round 7
// 160.774 us; speedup vs baseline: 1.2269x; 1.0209x over previous
//
#include <hip/hip_runtime.h>
#include <hip/hip_bf16.h>

// B=4, S=4096, D=1024, H=64.
// qs = LN(x@Wq), ks = LN(x@Wk), vs = x@Wv; out = softmax(qs ks^T/8) @ vs.
//  - No online softmax (LN rows have ||r||=8 -> |score|<=8); exp2 with log2e
//    folded into q's LN scale.
//  - k_attn r7: S computed TRANSPOSED (A=K, B=Q-regs) so P^T C-frags are
//    directly the B-operand of K=16 PV MFMAs -> P never touches LDS.
//    Wave (wq,wk) owns 32q x 32keys. LDS ops/wave-iter: 60 -> ~24.
//  - k_proj: r6 validated (staged, BK=64, reg prefetch).

typedef __bf16 bf16x8 __attribute__((ext_vector_type(8)));
typedef __bf16 bf16x4 __attribute__((ext_vector_type(4)));
typedef short s16x4 __attribute__((ext_vector_type(4)));
typedef float f32x4 __attribute__((ext_vector_type(4)));

#define NROW 16384
#define DD   1024
#define HH   64
#define SS   4096
#define LS   68

#if __has_builtin(__builtin_amdgcn_mfma_f32_16x16x16_bf16)
#define MFMA16(a, b, c) __builtin_amdgcn_mfma_f32_16x16x16_bf16((a), (b), (c), 0, 0, 0)
#define HAVE_MFMA16 1
#elif __has_builtin(__builtin_amdgcn_mfma_f32_16x16x16bf16_1k)
#define MFMA16(a, b, c)                                             \
  __builtin_amdgcn_mfma_f32_16x16x16bf16_1k(                        \
      __builtin_bit_cast(s16x4, (a)), __builtin_bit_cast(s16x4, (b)), (c), 0, 0, 0)
#define HAVE_MFMA16 1
#endif

static __device__ inline unsigned short f2bf_u(float x) {
  __bf16 b = (__bf16)x;
  return __builtin_bit_cast(unsigned short, b);
}
static __device__ inline uint2 pk4f(float a, float b, float c, float d) {
  return make_uint2((unsigned)f2bf_u(a) | ((unsigned)f2bf_u(b) << 16),
                    (unsigned)f2bf_u(c) | ((unsigned)f2bf_u(d) << 16));
}
static __device__ inline bf16x8 ld8(const __bf16* p) {
  bf16x4 lo = *reinterpret_cast<const bf16x4*>(p);
  bf16x4 hi = *reinterpret_cast<const bf16x4*>(p + 4);
  return __builtin_shufflevector(lo, hi, 0, 1, 2, 3, 4, 5, 6, 7);
}

// ---------------------------------------------------------------- kernel 1
__global__ __launch_bounds__(256) void k_transpose_w(
    const float* __restrict__ Wq, const float* __restrict__ Wk,
    const float* __restrict__ Wv, __bf16* __restrict__ WT) {
  int idx = blockIdx.x * 256 + threadIdx.x;   // 0..196607
  int mat = idx >> 16;
  int rem = idx & 65535;                      // k*64 + h (coalesced read)
  int k = rem >> 6, h = rem & 63;
  const float* W = (mat == 0) ? Wq : ((mat == 1) ? Wk : Wv);
  WT[(size_t)(mat * 64 + h) * DD + k] = (__bf16)W[rem];
}

// ---------------------------------------------------------------- kernel 2
// (r6-validated) Staged projection GEMM, BK=64. 32 rows, 2 waves; wave w
// owns rows 16w..16w+15 x all 12 N-tiles; LN fully in registers.
__global__ __launch_bounds__(128, 2) void k_proj(
    const float* __restrict__ X, const __bf16* __restrict__ WT,
    __bf16* __restrict__ qb, __bf16* __restrict__ kbp, __bf16* __restrict__ vT) {
  __shared__ __bf16 Xs[32 * LS];
  __shared__ __bf16 Ws[192 * LS];
  const int t = threadIdx.x, lane = t & 63, w = t >> 6;
  const int quad = lane >> 4, m = lane & 15;
  const int Mb = blockIdx.x * 32;

  f32x4 acc[12];
#pragma unroll
  for (int i = 0; i < 12; i++) acc[i] = (f32x4){0.f, 0.f, 0.f, 0.f};

  float4 xr[4];
  bf16x8 wr[12];
#pragma unroll
  for (int i = 0; i < 4; i++) {
    int c = t + i * 128, row = c >> 4, col = (c & 15) * 4;
    xr[i] = *reinterpret_cast<const float4*>(&X[(size_t)(Mb + row) * DD + col]);
  }
#pragma unroll
  for (int i = 0; i < 12; i++) {
    int c = t + i * 128, row = c >> 3, col = (c & 7) * 8;
    wr[i] = *reinterpret_cast<const bf16x8*>(&WT[(size_t)row * DD + col]);
  }

  for (int s = 0; s < 16; s++) {
    if (s) __syncthreads();
#pragma unroll
    for (int i = 0; i < 4; i++) {
      int c = t + i * 128, row = c >> 4, col = (c & 15) * 4;
      *reinterpret_cast<uint2*>(&Xs[row * LS + col]) =
          pk4f(xr[i].x, xr[i].y, xr[i].z, xr[i].w);
    }
#pragma unroll
    for (int i = 0; i < 12; i++) {
      int c = t + i * 128, row = c >> 3, col = (c & 7) * 8;
      uint4 raw = __builtin_bit_cast(uint4, wr[i]);
      __bf16* wd = &Ws[row * LS + col];
      *reinterpret_cast<uint2*>(wd) = make_uint2(raw.x, raw.y);
      *reinterpret_cast<uint2*>(wd + 4) = make_uint2(raw.z, raw.w);
    }
    __syncthreads();
    if (s + 1 < 16) {
      const int ko = (s + 1) * 64;
#pragma unroll
      for (int i = 0; i < 4; i++) {
        int c = t + i * 128, row = c >> 4, col = (c & 15) * 4;
        xr[i] = *reinterpret_cast<const float4*>(
            &X[(size_t)(Mb + row) * DD + ko + col]);
      }
#pragma unroll
      for (int i = 0; i < 12; i++) {
        int c = t + i * 128, row = c >> 3, col = (c & 7) * 8;
        wr[i] = *reinterpret_cast<const bf16x8*>(
            &WT[(size_t)row * DD + ko + col]);
      }
    }
#pragma unroll
    for (int kk = 0; kk < 2; kk++) {
      bf16x8 a = ld8(&Xs[(16 * w + m) * LS + 32 * kk + quad * 8]);
#pragma unroll
      for (int nt = 0; nt < 12; nt++) {
        bf16x8 bfr = ld8(&Ws[(16 * nt + m) * LS + 32 * kk + quad * 8]);
        acc[nt] = __builtin_amdgcn_mfma_f32_16x16x32_bf16(a, bfr, acc[nt], 0, 0, 0);
      }
    }
  }

#pragma unroll
  for (int mat = 0; mat < 2; mat++) {
#pragma unroll
    for (int reg = 0; reg < 4; reg++) {
      float s = 0.f, s2 = 0.f;
#pragma unroll
      for (int ntl = 0; ntl < 4; ntl++) {
        float x = acc[mat * 4 + ntl][reg];
        s += x; s2 += x * x;
      }
#pragma unroll
      for (int off = 1; off < 16; off <<= 1) {
        s += __shfl_xor(s, off, 64);
        s2 += __shfl_xor(s2, off, 64);
      }
      float mu = s * (1.0f / 64.0f);
      float var = s2 * (1.0f / 64.0f) - mu * mu;
      float rstd = rsqrtf(var + 1e-5f);
      float scl = (mat == 0) ? 0.125f * 1.44269504f * rstd : rstd;
#pragma unroll
      for (int ntl = 0; ntl < 4; ntl++)
        acc[mat * 4 + ntl][reg] = (acc[mat * 4 + ntl][reg] - mu) * scl;
    }
  }

  const int rowbase = Mb + 16 * w + quad * 4;
#pragma unroll
  for (int nt = 0; nt < 4; nt++)
#pragma unroll
    for (int reg = 0; reg < 4; reg++) {
      qb[(size_t)(rowbase + reg) * HH + m + 16 * nt] = (__bf16)acc[nt][reg];
      kbp[(size_t)(rowbase + reg) * HH + m + 16 * nt] = (__bf16)acc[4 + nt][reg];
    }
  const int b = Mb >> 12;
  const int s0 = (Mb & 4095) + 16 * w + quad * 4;
#pragma unroll
  for (int nt = 0; nt < 4; nt++) {
    ushort4 pk = make_ushort4(f2bf_u(acc[8 + nt][0]), f2bf_u(acc[8 + nt][1]),
                              f2bf_u(acc[8 + nt][2]), f2bf_u(acc[8 + nt][3]));
    *reinterpret_cast<ushort4*>(
        &vT[((size_t)(b * 64) + m + 16 * nt) * SS + s0]) = pk;
  }
}

// ---------------------------------------------------------------- kernel 3
// S^T attention. Block = 64 q x KV-split; wave (wq,wk) owns q-tiles
// {2wq,2wq+1} x key-subtiles {2wk,2wk+1} of each 64-key iter. P stays in
// registers (S^T C-layout == PV B-operand layout). O reduced across wk via
// LDS once; Op stored [sp][q][h] (true h columns).
__global__ __launch_bounds__(256, 4) void k_attn(
    const __bf16* __restrict__ qb, const __bf16* __restrict__ kbp,
    const __bf16* __restrict__ vT, float* __restrict__ Op,
    float* __restrict__ lp, int spbits) {
  __shared__ __align__(16) char smem[17408];
  __bf16* Klds = (__bf16*)smem;              // [64 keys][h], stride LS
  __bf16* Vlds = (__bf16*)(smem + 8704);     // [64 h][key], stride LS
  const int t = threadIdx.x, lane = t & 63, w = t >> 6;
  const int quad = lane >> 4, m = lane & 15;
  const int wq = w >> 1, wk = w & 1;
  const int nsp = 1 << spbits;
  const int qt = blockIdx.x >> spbits, sp = blockIdx.x & (nsp - 1);
  const int KPS = SS >> spbits;
  const int Mb = qt * 64;
  const int b = Mb >> 12;
  const size_t kvbase = (size_t)b * SS * HH;

  // Q fragments (B-operand): [ntl][kk]
  bf16x8 qf[2][2];
#pragma unroll
  for (int ntl = 0; ntl < 2; ntl++)
#pragma unroll
    for (int kk = 0; kk < 2; kk++)
      qf[ntl][kk] = *reinterpret_cast<const bf16x8*>(
          &qb[(size_t)(Mb + (2 * wq + ntl) * 16 + m) * HH + 32 * kk + quad * 8]);

  f32x4 O[4][2];   // [ht][ntl]
#pragma unroll
  for (int i = 0; i < 4; i++)
#pragma unroll
    for (int j = 0; j < 2; j++) O[i][j] = (f32x4){0.f, 0.f, 0.f, 0.f};
  float ll[2] = {0.f, 0.f};

  const int c0row = t >> 3, ck0 = (t & 7) * 8;
  const int c1row = c0row + 32;
  const int kb_lo = sp * KPS, kb_hi = kb_lo + KPS;

  uint4 kd0, kd1, vd0, vd1;
  kd0 = *reinterpret_cast<const uint4*>(&kbp[kvbase + (size_t)(kb_lo + c0row) * HH + ck0]);
  kd1 = *reinterpret_cast<const uint4*>(&kbp[kvbase + (size_t)(kb_lo + c1row) * HH + ck0]);
  vd0 = *reinterpret_cast<const uint4*>(&vT[(size_t)(b * 64 + c0row) * SS + kb_lo + ck0]);
  vd1 = *reinterpret_cast<const uint4*>(&vT[(size_t)(b * 64 + c1row) * SS + kb_lo + ck0]);

  for (int kb0 = kb_lo; kb0 < kb_hi; kb0 += 64) {
    {
      __bf16* kp0 = &Klds[c0row * LS + ck0];
      __bf16* kp1 = &Klds[c1row * LS + ck0];
      __bf16* vp0 = &Vlds[c0row * LS + ck0];
      __bf16* vp1 = &Vlds[c1row * LS + ck0];
      *reinterpret_cast<uint2*>(kp0) = make_uint2(kd0.x, kd0.y);
      *reinterpret_cast<uint2*>(kp0 + 4) = make_uint2(kd0.z, kd0.w);
      *reinterpret_cast<uint2*>(kp1) = make_uint2(kd1.x, kd1.y);
      *reinterpret_cast<uint2*>(kp1 + 4) = make_uint2(kd1.z, kd1.w);
      *reinterpret_cast<uint2*>(vp0) = make_uint2(vd0.x, vd0.y);
      *reinterpret_cast<uint2*>(vp0 + 4) = make_uint2(vd0.z, vd0.w);
      *reinterpret_cast<uint2*>(vp1) = make_uint2(vd1.x, vd1.y);
      *reinterpret_cast<uint2*>(vp1 + 4) = make_uint2(vd1.z, vd1.w);
    }
    __syncthreads();
    if (kb0 + 64 < kb_hi) {
      kd0 = *reinterpret_cast<const uint4*>(&kbp[kvbase + (size_t)(kb0 + 64 + c0row) * HH + ck0]);
      kd1 = *reinterpret_cast<const uint4*>(&kbp[kvbase + (size_t)(kb0 + 64 + c1row) * HH + ck0]);
      vd0 = *reinterpret_cast<const uint4*>(&vT[(size_t)(b * 64 + c0row) * SS + kb0 + 64 + ck0]);
      vd1 = *reinterpret_cast<const uint4*>(&vT[(size_t)(b * 64 + c1row) * SS + kb0 + 64 + ck0]);
    }

#pragma unroll
    for (int ktl = 0; ktl < 2; ktl++) {
      const int kt = 2 * wk + ktl;
      // S^T = K Q^T : A = K rows (keys as M), B = Q regs
      f32x4 sc[2];
      sc[0] = (f32x4){0.f, 0.f, 0.f, 0.f};
      sc[1] = (f32x4){0.f, 0.f, 0.f, 0.f};
#pragma unroll
      for (int kk = 0; kk < 2; kk++) {
        bf16x8 kf = ld8(&Klds[(kt * 16 + m) * LS + 32 * kk + quad * 8]);
        sc[0] = __builtin_amdgcn_mfma_f32_16x16x32_bf16(kf, qf[0][kk], sc[0], 0, 0, 0);
        sc[1] = __builtin_amdgcn_mfma_f32_16x16x32_bf16(kf, qf[1][kk], sc[1], 0, 0, 0);
      }
#pragma unroll
      for (int ntl = 0; ntl < 2; ntl++) {
        float p0 = exp2f(sc[ntl][0]), p1 = exp2f(sc[ntl][1]);
        float p2 = exp2f(sc[ntl][2]), p3 = exp2f(sc[ntl][3]);
        ll[ntl] += (p0 + p1) + (p2 + p3);
        bf16x4 pf;
        pf[0] = (__bf16)p0; pf[1] = (__bf16)p1;
        pf[2] = (__bf16)p2; pf[3] = (__bf16)p3;
#ifdef HAVE_MFMA16
#pragma unroll
        for (int ht = 0; ht < 4; ht++) {
          bf16x4 vf = *reinterpret_cast<const bf16x4*>(
              &Vlds[(16 * ht + m) * LS + kt * 16 + quad * 4]);
          O[ht][ntl] = MFMA16(vf, pf, O[ht][ntl]);
        }
#else
        // Fallback: build zero-padded K=32 B-frag via cross-lane moves.
        uint2 pd = __builtin_bit_cast(uint2, pf);
        int lo_src = 32 * quad + m, hi_src = 32 * quad + 16 + m;
        unsigned b0 = (unsigned)__shfl((int)pd.x, lo_src, 64);
        unsigned b1 = (unsigned)__shfl((int)pd.y, lo_src, 64);
        unsigned b2 = (unsigned)__shfl((int)pd.x, hi_src, 64);
        unsigned b3 = (unsigned)__shfl((int)pd.y, hi_src, 64);
        uint4 bz = (quad < 2) ? make_uint4(b0, b1, b2, b3)
                              : make_uint4(0u, 0u, 0u, 0u);
        bf16x8 bfrag = __builtin_bit_cast(bf16x8, bz);
#pragma unroll
        for (int ht = 0; ht < 4; ht++) {
          bf16x8 vf = ld8(&Vlds[(16 * ht + m) * LS + kt * 16 + (quad & 1) * 8]);
          O[ht][ntl] =
              __builtin_amdgcn_mfma_f32_16x16x32_bf16(vf, bfrag, O[ht][ntl], 0, 0, 0);
        }
#endif
      }
    }
    __syncthreads();
  }

  // l: sum over quads (keys quad*4+reg within the wave's subtiles)
#pragma unroll
  for (int ntl = 0; ntl < 2; ntl++) {
    ll[ntl] += __shfl_xor(ll[ntl], 16, 64);
    ll[ntl] += __shfl_xor(ll[ntl], 32, 64);
  }

  // ---- cross-wk reduce via LDS (union over K/V buffers), then store
  float* obuf = (float*)smem;            // [wq][64 h][stride 33]
  float* lbuf = (float*)(smem + 16896);  // 64 floats
  __syncthreads();
  if (wk == 1) {
#pragma unroll
    for (int ht = 0; ht < 4; ht++)
#pragma unroll
      for (int ntl = 0; ntl < 2; ntl++)
#pragma unroll
        for (int reg = 0; reg < 4; reg++)
          obuf[wq * 2112 + (16 * ht + quad * 4 + reg) * 33 + ntl * 16 + m] =
              O[ht][ntl][reg];
    if (quad == 0) {
      lbuf[(2 * wq + 0) * 16 + m] = ll[0];
      lbuf[(2 * wq + 1) * 16 + m] = ll[1];
    }
  }
  __syncthreads();
  if (wk == 0) {
#pragma unroll
    for (int ht = 0; ht < 4; ht++)
#pragma unroll
      for (int ntl = 0; ntl < 2; ntl++)
#pragma unroll
        for (int reg = 0; reg < 4; reg++)
          O[ht][ntl][reg] +=
              obuf[wq * 2112 + (16 * ht + quad * 4 + reg) * 33 + ntl * 16 + m];
#pragma unroll
    for (int ntl = 0; ntl < 2; ntl++) {
      const int qg = Mb + (2 * wq + ntl) * 16 + m;
      ll[ntl] += lbuf[(2 * wq + ntl) * 16 + m];
#pragma unroll
      for (int ht = 0; ht < 4; ht++) {
        f32x4 v = O[ht][ntl];
        *reinterpret_cast<float4*>(
            &Op[((size_t)sp * NROW + qg) * HH + 16 * ht + 4 * quad]) =
            make_float4(v[0], v[1], v[2], v[3]);
      }
      if (quad == 0) lp[sp * NROW + qg] = ll[ntl];
    }
  }
}

// ---------------------------------------------------------------- kernel 4
// Op is [sp][q][h] (true h) -> fully coalesced reads and writes.
__global__ __launch_bounds__(256) void k_comb(const float* __restrict__ Op,
                                              const float* __restrict__ lp,
                                              float* __restrict__ out, int nsp) {
  int idx = blockIdx.x * 256 + threadIdx.x;   // < NROW*HH
  int row = idx >> 6;
  float o = 0.f, l = 0.f;
  for (int j = 0; j < nsp; j++) {
    o += Op[(size_t)j * NROW * HH + idx];
    l += lp[j * NROW + row];
  }
  out[idx] = o / l;
}

// ---------------------------------------------------------------- launch
extern "C" void kernel_launch(void* const* d_in, const int* in_sizes, int n_in,
                              void* d_out, int out_size, void* d_ws, size_t ws_size,
                              hipStream_t stream) {
  const float* X  = (const float*)d_in[0];
  const float* Wq = (const float*)d_in[1];
  const float* Wk = (const float*)d_in[2];
  const float* Wv = (const float*)d_in[3];
  float* out = (float*)d_out;
  char* ws = (char*)d_ws;

  __bf16* WT  = (__bf16*)(ws);                          // 384 KB
  __bf16* qb  = (__bf16*)(ws + (size_t)512 * 1024);     // 2 MB
  __bf16* kbp = (__bf16*)(ws + (size_t)2560 * 1024);    // 2 MB
  __bf16* vT  = (__bf16*)(ws + (size_t)4608 * 1024);    // 2 MB
  float*  Op  = (float*)(ws + (size_t)6656 * 1024);     // nsp * 4 MB
  const size_t need8 = (size_t)(6656 + 8 * 4096 + 512) * 1024;
  const int spbits = (ws_size >= need8) ? 3 : 2;
  const int nsp = 1 << spbits;
  float* lp = (float*)(ws + (size_t)(6656 + nsp * 4096) * 1024);

  hipLaunchKernelGGL(k_transpose_w, dim3(768), dim3(256), 0, stream, Wq, Wk, Wv, WT);
  hipLaunchKernelGGL(k_proj, dim3(NROW / 32), dim3(128), 0, stream, X, WT, qb, kbp, vT);
  hipLaunchKernelGGL(k_attn, dim3((NROW / 64) * nsp), dim3(256), 0, stream,
                     qb, kbp, vT, Op, lp, spbits);
  hipLaunchKernelGGL(k_comb, dim3(NROW * HH / 256), dim3(256), 0, stream,
                     Op, lp, out, nsp);
}